// Round 1
// baseline (249.487 us; speedup 1.0000x reference)
//
#include <hip/hip_runtime.h>
#include <hip/hip_bf16.h>

#define N_ROWS 4096
#define TWO_N  8192
#define D      256

// exp(s / 0.07) = exp2(s * log2(e)/0.07)
__device__ __constant__ float kExpScale = 20.6099273924453f;   // 1.4426950408889634/0.07
__device__ __constant__ float kInvT     = 14.285714285714286f; // 1/0.07

typedef __attribute__((ext_vector_type(8))) short short8;
typedef __attribute__((ext_vector_type(4))) float f32x4;

static __device__ inline unsigned short f2bf(float x) {
    __hip_bfloat16 h = __float2bfloat16(x);
    return __builtin_bit_cast(unsigned short, h);
}

// One wave per row: L2-normalize, write bf16 row. Also zero S.
__global__ __launch_bounds__(256) void normalize_kernel(
        const float* __restrict__ emb_i, const float* __restrict__ emb_j,
        unsigned short* __restrict__ z, float* __restrict__ S) {
    const int gtid = blockIdx.x * 256 + threadIdx.x;
    if (gtid < TWO_N) S[gtid] = 0.0f;

    const int row  = (blockIdx.x * 256 + threadIdx.x) >> 6;   // one wave per row
    const int lane = threadIdx.x & 63;
    if (row >= TWO_N) return;

    const float* src = (row < N_ROWS) ? emb_i + (size_t)row * D
                                      : emb_j + (size_t)(row - N_ROWS) * D;
    float4 v = reinterpret_cast<const float4*>(src)[lane];
    float ss = v.x * v.x + v.y * v.y + v.z * v.z + v.w * v.w;
    #pragma unroll
    for (int m = 1; m < 64; m <<= 1) ss += __shfl_xor(ss, m);
    const float rn = 1.0f / fmaxf(sqrtf(ss), 1e-12f);

    ushort4 o;
    o.x = f2bf(v.x * rn);
    o.y = f2bf(v.y * rn);
    o.z = f2bf(v.z * rn);
    o.w = f2bf(v.w * rn);
    reinterpret_cast<ushort4*>(z + (size_t)row * D)[lane] = o;
}

// Flash-style: per block = 64 rows x 1024 cols. 4 waves, each wave 16 rows.
// A frags in registers (whole K=256), B frags streamed from global (L2-hot).
__global__ __launch_bounds__(256) void simexp_kernel(
        const unsigned short* __restrict__ z,
        float* __restrict__ S, float* __restrict__ posv) {
    const int lane  = threadIdx.x & 63;
    const int wave  = threadIdx.x >> 6;
    const int lmod  = lane & 15;
    const int lhi   = lane >> 4;
    const int rbase = blockIdx.x * 64 + wave * 16;
    const int cbase = blockIdx.y * 1024;

    // A fragment: lane holds row (lane&15), k = ks*32 + (lane>>4)*8 + [0..7]
    short8 a[8];
    const unsigned short* arow = z + (size_t)(rbase + lmod) * D + lhi * 8;
    #pragma unroll
    for (int ks = 0; ks < 8; ++ks)
        a[ks] = *reinterpret_cast<const short8*>(arow + ks * 32);

    const int row0 = rbase + lhi * 4;   // C layout: row=(lane>>4)*4+r, col=lane&15
    float sum[4] = {0.f, 0.f, 0.f, 0.f};

    for (int c0 = cbase; c0 < cbase + 1024; c0 += 16) {
        const unsigned short* brow = z + (size_t)(c0 + lmod) * D + lhi * 8;
        f32x4 acc = {0.f, 0.f, 0.f, 0.f};
        #pragma unroll
        for (int ks = 0; ks < 8; ++ks) {
            short8 b = *reinterpret_cast<const short8*>(brow + ks * 32);
            acc = __builtin_amdgcn_mfma_f32_16x16x32_bf16(a[ks], b, acc, 0, 0, 0);
        }
        const int col = c0 + lmod;
        #pragma unroll
        for (int r = 0; r < 4; ++r) {
            const int row = row0 + r;
            const float s = acc[r];
            if (col == (row ^ N_ROWS)) posv[row] = s;       // positive pair
            const float e = exp2f(s * kExpScale);
            sum[r] += (col != row) ? e : 0.0f;              // exclude diagonal
        }
    }

    // Reduce across the 16 lanes that share a row, then one atomic per row.
    #pragma unroll
    for (int r = 0; r < 4; ++r) {
        float v = sum[r];
        v += __shfl_xor(v, 1);
        v += __shfl_xor(v, 2);
        v += __shfl_xor(v, 4);
        v += __shfl_xor(v, 8);
        if (lmod == 0) atomicAdd(&S[row0 + r], v);
    }
}

__global__ __launch_bounds__(256) void finalize_kernel(
        const float* __restrict__ S, const float* __restrict__ posv,
        float* __restrict__ out) {
    const int tid = threadIdx.x;
    float local = 0.0f;
    for (int i = tid; i < TWO_N; i += 256)
        local += logf(S[i]) - posv[i] * kInvT;
    #pragma unroll
    for (int m = 1; m < 64; m <<= 1) local += __shfl_xor(local, m);
    __shared__ float red[4];
    if ((tid & 63) == 0) red[tid >> 6] = local;
    __syncthreads();
    if (tid == 0) out[0] = (red[0] + red[1] + red[2] + red[3]) / (float)TWO_N;
}

extern "C" void kernel_launch(void* const* d_in, const int* in_sizes, int n_in,
                              void* d_out, int out_size, void* d_ws, size_t ws_size,
                              hipStream_t stream) {
    const float* emb_i = (const float*)d_in[0];
    const float* emb_j = (const float*)d_in[1];
    float* out = (float*)d_out;

    unsigned short* z = (unsigned short*)d_ws;                       // 8192*256*2 = 4 MB
    float* S    = (float*)((char*)d_ws + (size_t)TWO_N * D * 2);     // 32 KB
    float* posv = S + TWO_N;                                         // 32 KB

    normalize_kernel<<<TWO_N / 4, 256, 0, stream>>>(emb_i, emb_j, z, S);
    simexp_kernel<<<dim3(TWO_N / 64, 8), 256, 0, stream>>>(z, S, posv);
    finalize_kernel<<<1, 256, 0, stream>>>(S, posv, out);
}

// Round 2
// 57.541 us; speedup vs baseline: 4.3358x; 4.3358x over previous
//
#include <hip/hip_runtime.h>
#include <hip/hip_bf16.h>

#define N_ROWS 4096
#define TWO_N  8192
#define D      256
#define DB     512                     // bytes per z row

// z is pre-scaled by sqrt(log2(e)/T) so sim' = sim * log2(e)/0.07 comes out of
// the MFMA ready for exp2. pos/T = sim' * ln2.
#define K_SQRT_SCALE 4.5398159980773926f   // sqrt(1.4426950408889634/0.07)
#define K_LN2        0.6931471805599453f

// simexp tiling
#define WAVES        4
#define ROWS_PER_WAVE 64               // 4 strips of 16
#define BLOCK_ROWS   (WAVES * ROWS_PER_WAVE)   // 256
#define COL_CHUNK    512
#define STAGE_COLS   64
#define NSTAGES      (COL_CHUNK / STAGE_COLS)  // 8

typedef __attribute__((ext_vector_type(8))) short short8;
typedef __attribute__((ext_vector_type(4))) float f32x4;

static __device__ inline unsigned short f2bf(float x) {
    __hip_bfloat16 h = __float2bfloat16(x);
    return __builtin_bit_cast(unsigned short, h);
}

// One wave per row: L2-normalize, scale, write bf16 row. Also zero S.
__global__ __launch_bounds__(256) void normalize_kernel(
        const float* __restrict__ emb_i, const float* __restrict__ emb_j,
        unsigned short* __restrict__ z, float* __restrict__ S) {
    const int gtid = blockIdx.x * 256 + threadIdx.x;
    if (gtid < TWO_N) S[gtid] = 0.0f;

    const int row  = gtid >> 6;        // one wave per row
    const int lane = threadIdx.x & 63;
    if (row >= TWO_N) return;

    const float* src = (row < N_ROWS) ? emb_i + (size_t)row * D
                                      : emb_j + (size_t)(row - N_ROWS) * D;
    float4 v = reinterpret_cast<const float4*>(src)[lane];
    float ss = v.x * v.x + v.y * v.y + v.z * v.z + v.w * v.w;
    #pragma unroll
    for (int m = 1; m < 64; m <<= 1) ss += __shfl_xor(ss, m);
    const float rn = K_SQRT_SCALE / fmaxf(sqrtf(ss), 1e-12f);

    ushort4 o;
    o.x = f2bf(v.x * rn);
    o.y = f2bf(v.y * rn);
    o.z = f2bf(v.z * rn);
    o.w = f2bf(v.w * rn);
    reinterpret_cast<ushort4*>(z + (size_t)row * D)[lane] = o;
}

// Block: 4 waves x 64 rows = 256 rows; col chunk 512, staged 64 cols at a time
// through swizzled LDS. A fragments live in registers for the whole block.
__global__ __launch_bounds__(256, 2) void simexp_kernel(
        const unsigned short* __restrict__ z,
        float* __restrict__ S, float* __restrict__ posv) {
    __shared__ unsigned short lds[STAGE_COLS * D];   // 32 KB, swizzled

    const int tid  = threadIdx.x;
    const int lane = tid & 63;
    const int wave = tid >> 6;
    const int lmod = lane & 15;
    const int lhi  = lane >> 4;

    const int R      = blockIdx.x * BLOCK_ROWS + wave * ROWS_PER_WAVE;
    const int cchunk = blockIdx.y * COL_CHUNK;

    // ---- A fragments: 4 strips x 8 k-steps, short8 (16B) each ----
    short8 a[4][8];
    #pragma unroll
    for (int s = 0; s < 4; ++s) {
        const unsigned short* arow = z + (size_t)(R + s * 16 + lmod) * D + lhi * 8;
        #pragma unroll
        for (int ks = 0; ks < 8; ++ks)
            a[s][ks] = *reinterpret_cast<const short8*>(arow + ks * 32);
    }

    // ---- staging addresses (linear LDS dest, inverse-swizzled global src) ----
    // Linear LDS byte L = i*4096 + tid*16. col = L>>9 = i*8 + (tid>>5),
    // off = (tid&31)<<4. Want LDS[col*512 + (kb ^ sw(col))] = G[col*512 + kb],
    // sw(col) = (col&7)<<4 and (col&7) == (tid>>5). So src = col*512 + (off^sw).
    const int colq = tid >> 5;                    // 0..7 == col&7 for all i
    const int offb = (tid & 31) << 4;
    const int soffbase = colq * 512 + (offb ^ (colq << 4));
    const int ldsbase  = tid * 16;

    float sums[4][4];
    #pragma unroll
    for (int s = 0; s < 4; ++s)
        #pragma unroll
        for (int r = 0; r < 4; ++r) sums[s][r] = 0.0f;

    const char* zbytes = (const char*)z;

    for (int st = 0; st < NSTAGES; ++st) {
        const int c0 = cchunk + st * STAGE_COLS;
        const char* src = zbytes + (size_t)c0 * DB + soffbase;
        #pragma unroll
        for (int i = 0; i < 8; ++i) {
            __builtin_amdgcn_global_load_lds(
                (const __attribute__((address_space(1))) unsigned int*)(src + i * 4096),
                (__attribute__((address_space(3))) unsigned int*)
                    ((char*)lds + ldsbase + i * 4096),
                16, 0, 0);
        }
        __syncthreads();   // compiler drains vmcnt before the barrier

        #pragma unroll
        for (int cs = 0; cs < 4; ++cs) {
            const int colL = cs * 16 + lmod;
            const int swz  = (colL & 7) << 4;
            const char* brow = (const char*)lds + colL * 512;

            f32x4 acc0 = {0.f, 0.f, 0.f, 0.f};
            f32x4 acc1 = {0.f, 0.f, 0.f, 0.f};
            f32x4 acc2 = {0.f, 0.f, 0.f, 0.f};
            f32x4 acc3 = {0.f, 0.f, 0.f, 0.f};
            #pragma unroll
            for (int ks = 0; ks < 8; ++ks) {
                short8 bk = *reinterpret_cast<const short8*>(
                    brow + (((ks * 64 + lhi * 16) ^ swz)));
                acc0 = __builtin_amdgcn_mfma_f32_16x16x32_bf16(a[0][ks], bk, acc0, 0, 0, 0);
                acc1 = __builtin_amdgcn_mfma_f32_16x16x32_bf16(a[1][ks], bk, acc1, 0, 0, 0);
                acc2 = __builtin_amdgcn_mfma_f32_16x16x32_bf16(a[2][ks], bk, acc2, 0, 0, 0);
                acc3 = __builtin_amdgcn_mfma_f32_16x16x32_bf16(a[3][ks], bk, acc3, 0, 0, 0);
            }

            const int csub = c0 + cs * 16;
            f32x4 accs[4] = {acc0, acc1, acc2, acc3};
            #pragma unroll
            for (int s = 0; s < 4; ++s) {
                const int rowt = R + s * 16;
                if (csub == rowt) {                       // diagonal subtile
                    #pragma unroll
                    for (int r = 0; r < 4; ++r) {
                        float e = __builtin_amdgcn_exp2f(accs[s][r]);
                        sums[s][r] += (lmod != lhi * 4 + r) ? e : 0.0f;
                    }
                } else if (csub == (rowt ^ N_ROWS)) {     // positive-pair subtile
                    #pragma unroll
                    for (int r = 0; r < 4; ++r) {
                        if (lmod == lhi * 4 + r)
                            posv[rowt + lhi * 4 + r] = accs[s][r];
                        sums[s][r] += __builtin_amdgcn_exp2f(accs[s][r]);
                    }
                } else {                                  // fast path
                    #pragma unroll
                    for (int r = 0; r < 4; ++r)
                        sums[s][r] += __builtin_amdgcn_exp2f(accs[s][r]);
                }
            }
        }
        __syncthreads();
    }

    // Reduce the 16 lmod-lanes sharing each row, one atomic per row.
    #pragma unroll
    for (int s = 0; s < 4; ++s)
        #pragma unroll
        for (int r = 0; r < 4; ++r) {
            float v = sums[s][r];
            v += __shfl_xor(v, 1);
            v += __shfl_xor(v, 2);
            v += __shfl_xor(v, 4);
            v += __shfl_xor(v, 8);
            if (lmod == 0) atomicAdd(&S[R + s * 16 + lhi * 4 + r], v);
        }
}

__global__ __launch_bounds__(256) void finalize_kernel(
        const float* __restrict__ S, const float* __restrict__ posv,
        float* __restrict__ out) {
    const int tid = threadIdx.x;
    float local = 0.0f;
    for (int i = tid; i < TWO_N; i += 256)
        local += logf(S[i]) - posv[i] * K_LN2;   // posv is sim*log2e/T
    #pragma unroll
    for (int m = 1; m < 64; m <<= 1) local += __shfl_xor(local, m);
    __shared__ float red[4];
    if ((tid & 63) == 0) red[tid >> 6] = local;
    __syncthreads();
    if (tid == 0) out[0] = (red[0] + red[1] + red[2] + red[3]) / (float)TWO_N;
}

extern "C" void kernel_launch(void* const* d_in, const int* in_sizes, int n_in,
                              void* d_out, int out_size, void* d_ws, size_t ws_size,
                              hipStream_t stream) {
    const float* emb_i = (const float*)d_in[0];
    const float* emb_j = (const float*)d_in[1];
    float* out = (float*)d_out;

    unsigned short* z = (unsigned short*)d_ws;                    // 4 MB
    float* S    = (float*)((char*)d_ws + (size_t)TWO_N * D * 2);  // 32 KB
    float* posv = S + TWO_N;                                      // 32 KB

    normalize_kernel<<<TWO_N / 4, 256, 0, stream>>>(emb_i, emb_j, z, S);
    simexp_kernel<<<dim3(TWO_N / BLOCK_ROWS, TWO_N / COL_CHUNK), 256, 0, stream>>>(z, S, posv);
    finalize_kernel<<<1, 256, 0, stream>>>(S, posv, out);
}

// Round 3
// 48.915 us; speedup vs baseline: 5.1005x; 1.1764x over previous
//
#include <hip/hip_runtime.h>
#include <hip/hip_bf16.h>

#define N_ROWS 4096
#define TWO_N  8192
#define D      256
#define DB     512                     // bytes per z row

// z is pre-scaled by sqrt(log2(e)/T) so sim' = sim * log2(e)/0.07 comes out of
// the MFMA ready for exp2. pos/T = sim' * ln2.
#define K_SQRT_SCALE 4.5398159980773926f   // sqrt(1.4426950408889634/0.07)
#define K_LN2        0.6931471805599453f

// simexp tiling
#define WAVES        4
#define ROWS_PER_WAVE 64               // 4 strips of 16
#define BLOCK_ROWS   (WAVES * ROWS_PER_WAVE)   // 256
#define COL_CHUNK    512
#define STAGE_COLS   64
#define NSTAGES      (COL_CHUNK / STAGE_COLS)  // 8

typedef __attribute__((ext_vector_type(8))) short short8;
typedef __attribute__((ext_vector_type(4))) float f32x4;

static __device__ inline unsigned short f2bf(float x) {
    __hip_bfloat16 h = __float2bfloat16(x);
    return __builtin_bit_cast(unsigned short, h);
}

// One wave per row: L2-normalize, scale, write bf16 row. Also zero S.
__global__ __launch_bounds__(256) void normalize_kernel(
        const float* __restrict__ emb_i, const float* __restrict__ emb_j,
        unsigned short* __restrict__ z, float* __restrict__ S) {
    const int gtid = blockIdx.x * 256 + threadIdx.x;
    if (gtid < TWO_N) S[gtid] = 0.0f;

    const int row  = gtid >> 6;        // one wave per row
    const int lane = threadIdx.x & 63;
    if (row >= TWO_N) return;

    const float* src = (row < N_ROWS) ? emb_i + (size_t)row * D
                                      : emb_j + (size_t)(row - N_ROWS) * D;
    float4 v = reinterpret_cast<const float4*>(src)[lane];
    float ss = v.x * v.x + v.y * v.y + v.z * v.z + v.w * v.w;
    #pragma unroll
    for (int m = 1; m < 64; m <<= 1) ss += __shfl_xor(ss, m);
    const float rn = K_SQRT_SCALE / fmaxf(sqrtf(ss), 1e-12f);

    ushort4 o;
    o.x = f2bf(v.x * rn);
    o.y = f2bf(v.y * rn);
    o.z = f2bf(v.z * rn);
    o.w = f2bf(v.w * rn);
    reinterpret_cast<ushort4*>(z + (size_t)row * D)[lane] = o;
}

// Block: 4 waves x 64 rows = 256 rows; col chunk 512, staged 64 cols at a time
// through double-buffered swizzled LDS (prefetch st+1 while computing st).
__global__ __launch_bounds__(256, 2) void simexp_kernel(
        const unsigned short* __restrict__ z,
        float* __restrict__ S, float* __restrict__ posv) {
    __shared__ unsigned short lds[2][STAGE_COLS * D];   // 2 x 32 KB, swizzled

    const int tid  = threadIdx.x;
    const int lane = tid & 63;
    const int wave = tid >> 6;
    const int lmod = lane & 15;
    const int lhi  = lane >> 4;

    const int R      = blockIdx.x * BLOCK_ROWS + wave * ROWS_PER_WAVE;
    const int cchunk = blockIdx.y * COL_CHUNK;

    // ---- A fragments: 4 strips x 8 k-steps, short8 (16B) each ----
    short8 a[4][8];
    #pragma unroll
    for (int s = 0; s < 4; ++s) {
        const unsigned short* arow = z + (size_t)(R + s * 16 + lmod) * D + lhi * 8;
        #pragma unroll
        for (int ks = 0; ks < 8; ++ks)
            a[s][ks] = *reinterpret_cast<const short8*>(arow + ks * 32);
    }

    // ---- staging addresses (linear LDS dest, inverse-swizzled global src) ----
    // Linear LDS byte L = i*4096 + tid*16. col = L>>9 = i*8 + (tid>>5),
    // off = (tid&31)<<4. Want LDS[col*512 + (kb ^ sw(col))] = G[col*512 + kb],
    // sw(col) = (col&7)<<4 and (col&7) == (tid>>5). So src = col*512 + (off^sw).
    const int colq = tid >> 5;                    // 0..7 == col&7 for all i
    const int offb = (tid & 31) << 4;
    const int soffbase = colq * 512 + (offb ^ (colq << 4));
    const int ldsbase  = tid * 16;

    const char* zbytes = (const char*)z;

    auto stage = [&](int st, int buf) {
        const char* src = zbytes + (size_t)(cchunk + st * STAGE_COLS) * DB + soffbase;
        char* dst = (char*)&lds[buf][0] + ldsbase;
        #pragma unroll
        for (int i = 0; i < 8; ++i) {
            __builtin_amdgcn_global_load_lds(
                (const __attribute__((address_space(1))) unsigned int*)(src + i * 4096),
                (__attribute__((address_space(3))) unsigned int*)(dst + i * 4096),
                16, 0, 0);
        }
    };

    float sums[4][4];
    #pragma unroll
    for (int s = 0; s < 4; ++s)
        #pragma unroll
        for (int r = 0; r < 4; ++r) sums[s][r] = 0.0f;

    stage(0, 0);
    __syncthreads();   // compiler drains vmcnt before the barrier

    for (int st = 0; st < NSTAGES; ++st) {
        if (st + 1 < NSTAGES) stage(st + 1, (st + 1) & 1);   // prefetch next

        const char* base = (const char*)&lds[st & 1][0];
        const int c0 = cchunk + st * STAGE_COLS;

        #pragma unroll
        for (int cs = 0; cs < 4; ++cs) {
            const int colL = cs * 16 + lmod;
            const int swz  = (colL & 7) << 4;
            const char* brow = base + colL * 512;

            f32x4 acc0 = {0.f, 0.f, 0.f, 0.f};
            f32x4 acc1 = {0.f, 0.f, 0.f, 0.f};
            f32x4 acc2 = {0.f, 0.f, 0.f, 0.f};
            f32x4 acc3 = {0.f, 0.f, 0.f, 0.f};
            #pragma unroll
            for (int ks = 0; ks < 8; ++ks) {
                short8 bk = *reinterpret_cast<const short8*>(
                    brow + (((ks * 64 + lhi * 16) ^ swz)));
                acc0 = __builtin_amdgcn_mfma_f32_16x16x32_bf16(a[0][ks], bk, acc0, 0, 0, 0);
                acc1 = __builtin_amdgcn_mfma_f32_16x16x32_bf16(a[1][ks], bk, acc1, 0, 0, 0);
                acc2 = __builtin_amdgcn_mfma_f32_16x16x32_bf16(a[2][ks], bk, acc2, 0, 0, 0);
                acc3 = __builtin_amdgcn_mfma_f32_16x16x32_bf16(a[3][ks], bk, acc3, 0, 0, 0);
            }

            const int csub = c0 + cs * 16;
            f32x4 accs[4] = {acc0, acc1, acc2, acc3};
            #pragma unroll
            for (int s = 0; s < 4; ++s) {
                const int rowt = R + s * 16;
                if (csub == rowt) {                       // diagonal subtile
                    #pragma unroll
                    for (int r = 0; r < 4; ++r) {
                        float e = __builtin_amdgcn_exp2f(accs[s][r]);
                        sums[s][r] += (lmod != lhi * 4 + r) ? e : 0.0f;
                    }
                } else if (csub == (rowt ^ N_ROWS)) {     // positive-pair subtile
                    #pragma unroll
                    for (int r = 0; r < 4; ++r) {
                        if (lmod == lhi * 4 + r)
                            posv[rowt + lhi * 4 + r] = accs[s][r];
                        sums[s][r] += __builtin_amdgcn_exp2f(accs[s][r]);
                    }
                } else {                                  // fast path
                    #pragma unroll
                    for (int r = 0; r < 4; ++r)
                        sums[s][r] += __builtin_amdgcn_exp2f(accs[s][r]);
                }
            }
        }
        __syncthreads();
    }

    // Reduce the 16 lmod-lanes sharing each row, one atomic per row.
    #pragma unroll
    for (int s = 0; s < 4; ++s)
        #pragma unroll
        for (int r = 0; r < 4; ++r) {
            float v = sums[s][r];
            v += __shfl_xor(v, 1);
            v += __shfl_xor(v, 2);
            v += __shfl_xor(v, 4);
            v += __shfl_xor(v, 8);
            if (lmod == 0) atomicAdd(&S[R + s * 16 + lhi * 4 + r], v);
        }
}

__global__ __launch_bounds__(1024) void finalize_kernel(
        const float* __restrict__ S, const float* __restrict__ posv,
        float* __restrict__ out) {
    const int tid = threadIdx.x;
    float local = 0.0f;
    #pragma unroll
    for (int i = tid; i < TWO_N; i += 1024)
        local += logf(S[i]) - posv[i] * K_LN2;   // posv is sim*log2e/T
    #pragma unroll
    for (int m = 1; m < 64; m <<= 1) local += __shfl_xor(local, m);
    __shared__ float red[16];
    if ((tid & 63) == 0) red[tid >> 6] = local;
    __syncthreads();
    if (tid == 0) {
        float t = 0.0f;
        #pragma unroll
        for (int w = 0; w < 16; ++w) t += red[w];
        out[0] = t / (float)TWO_N;
    }
}

extern "C" void kernel_launch(void* const* d_in, const int* in_sizes, int n_in,
                              void* d_out, int out_size, void* d_ws, size_t ws_size,
                              hipStream_t stream) {
    const float* emb_i = (const float*)d_in[0];
    const float* emb_j = (const float*)d_in[1];
    float* out = (float*)d_out;

    unsigned short* z = (unsigned short*)d_ws;                    // 4 MB
    float* S    = (float*)((char*)d_ws + (size_t)TWO_N * D * 2);  // 32 KB
    float* posv = S + TWO_N;                                      // 32 KB

    normalize_kernel<<<TWO_N / 4, 256, 0, stream>>>(emb_i, emb_j, z, S);
    simexp_kernel<<<dim3(TWO_N / BLOCK_ROWS, TWO_N / COL_CHUNK), 256, 0, stream>>>(z, S, posv);
    finalize_kernel<<<1, 1024, 0, stream>>>(S, posv, out);
}